// Round 15
// baseline (398.790 us; speedup 1.0000x reference)
//
#include <hip/hip_runtime.h>
#include <hip/hip_bf16.h>

#define B_ 8
#define N_ 4096
#define E_ 131072
#define D_ 64
#define H_ 128

#define EDGE_BLOCKS 1024
#define ETILE 64
#define TILES_TOTAL ((B_ * E_) / ETILE)               // 16384 tiles of 64 edges
#define TILES_PER_BLOCK (TILES_TOTAL / EDGE_BLOCKS)   // 16

typedef unsigned int u32;
typedef short bf16x8 __attribute__((ext_vector_type(8)));
typedef float f32x4 __attribute__((ext_vector_type(4)));

__device__ __forceinline__ unsigned short f2bf(float f) {
  u32 x = __float_as_uint(f);
  x += 0x7fffu + ((x >> 16) & 1u);   // RNE
  return (unsigned short)(x >> 16);
}
__device__ __forceinline__ float bf2f(unsigned short v) {
  return __uint_as_float(((u32)v) << 16);
}
__device__ __forceinline__ u32 cvt_pk_bf16(float lo, float hi) {
  u32 r;
  asm("v_cvt_pk_bf16_f32 %0, %1, %2" : "=v"(r) : "v"(lo), "v"(hi));
  return r;
}
__device__ __forceinline__ float silu_f(float x) { return x / (1.0f + __expf(-x)); }

// XOR-swizzled u16 index into a [rows][128] bf16 LDS tile (row stride 256 B).
__device__ __forceinline__ int swz(int row, int col) {
  return row * 128 + (col ^ ((row & 7) << 3));
}

#define MFMA(a, b, c) __builtin_amdgcn_mfma_f32_16x16x32_bf16(a, b, c, 0, 0, 0)

// ---------------- prep kernels ----------------
// P1[n] = nf[n] @ Wm1[0:64,:] + bm1 ; P2[n] = nf[n] @ Wm1[64:128,:]  (bf16 out)
__global__ __launch_bounds__(512) void p12_k(
    const float* __restrict__ nf, const float* __restrict__ Wm1,
    const float* __restrict__ bm1,
    unsigned short* __restrict__ P1, unsigned short* __restrict__ P2)
{
  __shared__ unsigned short sWa[128 * 64];   // [outcol][k], Wm1 rows 0-63
  __shared__ unsigned short sWb[128 * 64];   // Wm1 rows 64-127
  __shared__ unsigned short sNf[64 * 64];    // nf tile bf16

  const int tid = threadIdx.x;
  const int node0 = blockIdx.x * 64;

  for (int i = tid; i < 64 * 128; i += 512) {
    const int k = i >> 7, n = i & 127;
    const int d = n * 64 + (k ^ ((n & 7) << 3));
    sWa[d] = f2bf(Wm1[k * 128 + n]);
    sWb[d] = f2bf(Wm1[(64 + k) * 128 + n]);
  }
  {
    const int row = tid >> 3, c0 = 8 * (tid & 7);
    const float4 v0 = *(const float4*)&nf[(size_t)(node0 + row) * 64 + c0];
    const float4 v1 = *(const float4*)&nf[(size_t)(node0 + row) * 64 + c0 + 4];
    uint4 pk = make_uint4(cvt_pk_bf16(v0.x, v0.y), cvt_pk_bf16(v0.z, v0.w),
                          cvt_pk_bf16(v1.x, v1.y), cvt_pk_bf16(v1.z, v1.w));
    *(uint4*)&sNf[row * 64 + (c0 ^ ((row & 7) << 3))] = pk;
  }
  __syncthreads();

  const int lane = tid & 63;
  const int w = tid >> 6;              // 8 waves: w<4 -> P1 cols, w>=4 -> P2
  const int l15 = lane & 15;
  const int l4 = lane >> 4;
  const int k0l = l4 * 8;
  const int colbase = (w & 3) * 32;
  const int n0 = colbase + l15, n1 = n0 + 16;
  const unsigned short* sW = (w < 4) ? sWa : sWb;
  const float add0 = (w < 4) ? bm1[n0] : 0.f;
  const float add1 = (w < 4) ? bm1[n1] : 0.f;
  unsigned short* OUT = (w < 4) ? P1 : P2;

  f32x4 acc[4][2];
  {
    f32x4 z = {0.f, 0.f, 0.f, 0.f};
#pragma unroll
    for (int i = 0; i < 4; ++i) { acc[i][0] = z; acc[i][1] = z; }
  }
#pragma unroll
  for (int ks = 0; ks < 2; ++ks) {
    const int k = ks * 32 + k0l;
    bf16x8 b0 = *(const bf16x8*)&sW[n0 * 64 + (k ^ ((n0 & 7) << 3))];
    bf16x8 b1 = *(const bf16x8*)&sW[n1 * 64 + (k ^ ((n1 & 7) << 3))];
#pragma unroll
    for (int i = 0; i < 4; ++i) {
      const int row = 16 * i + l15;
      bf16x8 a = *(const bf16x8*)&sNf[row * 64 + (k ^ ((row & 7) << 3))];
      acc[i][0] = MFMA(a, b0, acc[i][0]);
      acc[i][1] = MFMA(a, b1, acc[i][1]);
    }
  }
#pragma unroll
  for (int i = 0; i < 4; ++i)
#pragma unroll
    for (int r = 0; r < 4; ++r) {
      const int m = 16 * i + l4 * 4 + r;
      OUT[(size_t)(node0 + m) * 128 + n0] = f2bf(acc[i][0][r] + add0);
      OUT[(size_t)(node0 + m) * 128 + n1] = f2bf(acc[i][1][r] + add1);
    }
}

__global__ void hist_k(const int* __restrict__ ei, int* __restrict__ hist) {
  const int e = blockIdx.x * 256 + threadIdx.x;
  atomicAdd(&hist[ei[E_ + e]], 1);
}

__global__ __launch_bounds__(1024) void scan4096(int* __restrict__ h) {
  __shared__ int wsums[16];
  const int tid = threadIdx.x;
  const int lane = tid & 63, wv = tid >> 6;
  int4 v = ((int4*)h)[tid];
  const int s = v.x + v.y + v.z + v.w;
  int incl = s;
#pragma unroll
  for (int off = 1; off < 64; off <<= 1) {
    int u = __shfl_up(incl, off);
    if (lane >= off) incl += u;
  }
  if (lane == 63) wsums[wv] = incl;
  __syncthreads();
  if (wv == 0) {
    int ws = (lane < 16) ? wsums[lane] : 0;
#pragma unroll
    for (int off = 1; off < 16; off <<= 1) {
      int u = __shfl_up(ws, off);
      if (lane >= off) ws += u;
    }
    if (lane < 16) wsums[lane] = ws;
  }
  __syncthreads();
  int base = (wv ? wsums[wv - 1] : 0) + (incl - s);
  int4 o;
  o.x = base; o.y = base + v.x; o.z = o.y + v.y; o.w = o.z + v.z;
  ((int4*)h)[tid] = o;
}

__global__ void scatter_k(const int* __restrict__ ei, int* __restrict__ offs,
                          int* __restrict__ src_s, int* __restrict__ dst_s) {
  const int e = blockIdx.x * 256 + threadIdx.x;
  const int d = ei[E_ + e];
  const int p = atomicAdd(&offs[d], 1);
  src_s[p] = ei[e];
  dst_s[p] = d;
}

// ---- edge kernel: 512 thr / 64-edge tiles / ~69 KB LDS -> 2 blocks per CU ----
__global__ __launch_bounds__(512, 4) void egnn_edge_mfma(
    const unsigned short* __restrict__ P1, const unsigned short* __restrict__ P2,
    const float* __restrict__ coords,
    const int* __restrict__ src_s, const int* __restrict__ dst_s,
    const float* __restrict__ Wm1,
    const float* __restrict__ Wm2, const float* __restrict__ bm2,
    const float* __restrict__ Wc1, const float* __restrict__ bc1,
    const float* __restrict__ Wc2, const float* __restrict__ bc2,
    float* __restrict__ agg, float* __restrict__ cdelta)
{
  __shared__ unsigned short sW2[128 * 128];       // 32 KB (Wm2^T swizzled)
  __shared__ unsigned short bufA[ETILE * 128];    // 16 KB: h tile
  __shared__ unsigned short bufB[ETILE * 128];    // 16 KB: m tile
  __shared__ float swr[128];                      // Wm1 row 128 (dist weights)
  __shared__ float4 sgeo[2][ETILE];               // 2 KB
  __shared__ int sdst[2][ETILE];                  // 0.5 KB
  __shared__ float swpart[8][ETILE];              // 2 KB

  const int tid = threadIdx.x;
  for (int i = tid; i < 128 * 128; i += 512) {
    const int k = i >> 7, n = i & 127;
    sW2[swz(n, k)] = f2bf(Wm2[i]);
  }
  if (tid < 128) swr[tid] = Wm1[128 * 128 + tid];

  const int lane = tid & 63;
  const int w = tid >> 6;              // 0..7
  const int l15 = lane & 15;
  const int l4 = lane >> 4;
  const int k0l = l4 * 8;
  const int rowbase = (w >> 2) * 32;   // {0,32}
  const int colbase = (w & 3) * 32;
  const int rA = rowbase + l15;
  const int rB = colbase + l15;
  const int n0 = colbase + l15;
  const int n1 = n0 + 16;
  const int n3 = w * 16 + l15;         // L3: 16-col group per wave

  const float bb2_0 = bm2[n0], bb2_1 = bm2[n1];
  const float bb3 = bc1[n3];
  const float wc2v = Wc2[n3];
  const float bc2v = bc2[0];

  // Wc1 B-fragments in registers (tile-invariant, 16 VGPRs; 512-thr block so
  // the allocator grants >64 VGPR - spill tell is WRITE_SIZE)
  bf16x8 w3f[4];
#pragma unroll
  for (int ks = 0; ks < 4; ++ks) {
    bf16x8 v;
#pragma unroll
    for (int j = 0; j < 8; ++j)
      v[j] = (short)f2bf(Wc1[(ks * 32 + k0l + j) * 128 + n3]);
    w3f[ks] = v;
  }

  const int m_t = tid >> 3;   // gather: 8 threads per edge row (0..63)
  const int q_t = tid & 7;    // 16-col group per thread

  // XCD swizzle: batch b owned by one XCD
  const int myblk = (blockIdx.x & 7) * (EDGE_BLOCKS / 8) + (blockIdx.x >> 3);
  const int b = myblk >> 7;                     // 128 blocks per batch
  const int gbase = (myblk & 127) * TILES_PER_BLOCK;

  __syncthreads();

  f32x4 acc[2][2];

  for (int t = 0; t < TILES_PER_BLOCK; ++t) {
    const int p = t & 1;
    const int ebase = (gbase + t) * ETILE;

    // ---- fused gather+L1: h = silu(P1[s] + P2[d] + dist*wr) -> bufA ----
    {
      const int e = ebase + m_t;
      const int s = src_s[e];
      const int d = dst_s[e];
      const float* cs = coords + (size_t)(b * N_ + s) * 3;
      const float* cd = coords + (size_t)(b * N_ + d) * 3;
      const float d0 = cd[0] - cs[0], d1 = cd[1] - cs[1], d2 = cd[2] - cs[2];
      const float dist = sqrtf(fmaf(d0, d0, fmaf(d1, d1, d2 * d2)));
      if (q_t == 0) {
        sdst[p][m_t] = d;
        sgeo[p][m_t] = make_float4(d0, d1, d2, dist);
      }
      const int c0 = 16 * q_t;
      const uint4* p1p = (const uint4*)(P1 + (size_t)(b * N_ + s) * 128 + c0);
      const uint4* p2p = (const uint4*)(P2 + (size_t)(b * N_ + d) * 128 + c0);
      uint4 xa = p1p[0], xb = p1p[1];
      uint4 ya = p2p[0], yb = p2p[1];
      u32 opk[8];
#pragma unroll
      for (int jj = 0; jj < 4; ++jj) {
        const float2 wr2 = *(const float2*)&swr[c0 + 2 * jj];
        const u32 xp = ((const u32*)&xa)[jj], yp = ((const u32*)&ya)[jj];
        const float lo = bf2f((unsigned short)xp) + bf2f((unsigned short)yp) + dist * wr2.x;
        const float hi = bf2f((unsigned short)(xp >> 16)) + bf2f((unsigned short)(yp >> 16)) + dist * wr2.y;
        opk[jj] = cvt_pk_bf16(silu_f(lo), silu_f(hi));
      }
#pragma unroll
      for (int jj = 0; jj < 4; ++jj) {
        const float2 wr2 = *(const float2*)&swr[c0 + 8 + 2 * jj];
        const u32 xp = ((const u32*)&xb)[jj], yp = ((const u32*)&yb)[jj];
        const float lo = bf2f((unsigned short)xp) + bf2f((unsigned short)yp) + dist * wr2.x;
        const float hi = bf2f((unsigned short)(xp >> 16)) + bf2f((unsigned short)(yp >> 16)) + dist * wr2.y;
        opk[4 + jj] = cvt_pk_bf16(silu_f(lo), silu_f(hi));
      }
      *(uint4*)&bufA[swz(m_t, c0)] = make_uint4(opk[0], opk[1], opk[2], opk[3]);
      *(uint4*)&bufA[swz(m_t, c0 + 8)] = make_uint4(opk[4], opk[5], opk[6], opk[7]);
    }
    __syncthreads();   // B1: h visible in bufA

    // ---- L2: m = h @ Wm2 + bm2 -> bufB ----
    {
      f32x4 z = {0.f, 0.f, 0.f, 0.f};
      acc[0][0] = z; acc[0][1] = z; acc[1][0] = z; acc[1][1] = z;
    }
#pragma unroll
    for (int ks = 0; ks < 4; ++ks) {
      const int k = ks * 32 + k0l;
      bf16x8 b0 = *(const bf16x8*)&sW2[swz(rB, k)];
      bf16x8 b1 = *(const bf16x8*)&sW2[swz(rB + 16, k)];
      bf16x8 a0 = *(const bf16x8*)&bufA[swz(rA, k)];
      bf16x8 a1 = *(const bf16x8*)&bufA[swz(rA + 16, k)];
      acc[0][0] = MFMA(a0, b0, acc[0][0]);
      acc[0][1] = MFMA(a0, b1, acc[0][1]);
      acc[1][0] = MFMA(a1, b0, acc[1][0]);
      acc[1][1] = MFMA(a1, b1, acc[1][1]);
    }
#pragma unroll
    for (int i = 0; i < 2; ++i)
#pragma unroll
      for (int r = 0; r < 4; ++r) {
        const int m = rowbase + 16 * i + l4 * 4 + r;
        const u32 pk = cvt_pk_bf16(acc[i][0][r] + bb2_0, acc[i][1][r] + bb2_1);
        bufB[swz(m, n0)] = (unsigned short)pk;
        bufB[swz(m, n1)] = (unsigned short)(pk >> 16);
      }
    __syncthreads();   // B2: m visible in bufB

    // ---- L3: c = silu(m @ Wc1 + bc1); partial w = c . Wc2 (B from regs) ----
    {
      f32x4 acc3[4];
      {
        f32x4 z = {0.f, 0.f, 0.f, 0.f};
        acc3[0] = z; acc3[1] = z; acc3[2] = z; acc3[3] = z;
      }
#pragma unroll
      for (int ks = 0; ks < 4; ++ks) {
        const int k = ks * 32 + k0l;
#pragma unroll
        for (int i = 0; i < 4; ++i) {
          bf16x8 a = *(const bf16x8*)&bufB[swz(16 * i + l15, k)];
          acc3[i] = MFMA(a, w3f[ks], acc3[i]);
        }
      }
#pragma unroll
      for (int i = 0; i < 4; ++i)
#pragma unroll
        for (int r = 0; r < 4; ++r) {
          float pw = silu_f(acc3[i][r] + bb3) * wc2v;
          pw += __shfl_xor(pw, 1);
          pw += __shfl_xor(pw, 2);
          pw += __shfl_xor(pw, 4);
          pw += __shfl_xor(pw, 8);
          if (l15 == 0) swpart[w][16 * i + l4 * 4 + r] = pw;
        }
    }

    // ---- agg run-reduction: 512 thr, (colpair=tid&63, 8-row group=tid>>6) ----
    {
      const int c0 = 2 * (tid & 63);
      int r = (tid >> 6) * 8;           // wave-uniform row group
      int cur = sdst[p][r];
      float a0s = 0.f, a1s = 0.f;
#pragma unroll 4
      for (int k = 0; k < 8; ++k, ++r) {
        const int d2 = sdst[p][r];
        if (d2 != cur) {   // uniform per wave
          float* bp2 = agg + ((size_t)(b * N_ + cur)) * H_ + c0;
          unsafeAtomicAdd(bp2, a0s);
          unsafeAtomicAdd(bp2 + 1, a1s);
          a0s = 0.f; a1s = 0.f;
          cur = d2;
        }
        const u32 pkr = *(const u32*)&bufB[swz(r, c0)];
        a0s += bf2f((unsigned short)pkr);
        a1s += bf2f((unsigned short)(pkr >> 16));
      }
      float* bp2 = agg + ((size_t)(b * N_ + cur)) * H_ + c0;
      unsafeAtomicAdd(bp2, a0s);
      unsafeAtomicAdd(bp2 + 1, a1s);
    }
    __syncthreads();   // B3: bufB reads done, swpart visible

    // ---- coord scatter: segmented scan over 64 sorted rows (wave 0) ----
    if (tid < ETILE) {
      float wc = bc2v;
#pragma unroll
      for (int cg = 0; cg < 8; ++cg) wc += swpart[cg][tid];
      const float4 g = sgeo[p][tid];
      const float inv = 1.0f / (g.w + 1e-8f);
      float vx = wc * g.x * inv, vy = wc * g.y * inv, vz = wc * g.z * inv;
      const int myd = sdst[p][tid];
      int flg = (tid == 0) ? 1 : (sdst[p][tid - 1] != myd);
#pragma unroll
      for (int off = 1; off < 64; off <<= 1) {
        float ux = __shfl_up(vx, off);
        float uy = __shfl_up(vy, off);
        float uz = __shfl_up(vz, off);
        int uf = __shfl_up(flg, off);
        if (lane >= off) {
          if (!flg) { vx += ux; vy += uy; vz += uz; }
          flg |= uf;
        }
      }
      const bool tail = (tid == ETILE - 1) || (sdst[p][tid + 1] != myd);
      if (tail) {
        float* bp = cdelta + ((size_t)(b * N_ + myd)) * 3;
        unsafeAtomicAdd(bp + 0, vx);
        unsafeAtomicAdd(bp + 1, vy);
        unsafeAtomicAdd(bp + 2, vz);
      }
    }
    // next gather writes bufA (last read pre-B2) and parity p^1 geo: safe
  }
}

// ---------------- node kernel: MFMA version (unchanged) ----------------
#define NTILE 128

__global__ __launch_bounds__(512) void egnn_node_mfma(
    const float* __restrict__ nf, const float* __restrict__ coords,
    const float* __restrict__ agg, const float* __restrict__ cdelta,
    const float* __restrict__ Wn1, const float* __restrict__ bn1,
    const float* __restrict__ Wn2, const float* __restrict__ bn2,
    float* __restrict__ out_nf, float* __restrict__ out_c)
{
  __shared__ unsigned short sA[128 * 192];
  __shared__ unsigned short sB[64 * 128];
  __shared__ unsigned short bufN[128 * 64];
  __shared__ unsigned short bufA[128 * 128];
  __shared__ unsigned short hbuf[128 * 128];

  const int tid = threadIdx.x;
  const int node0 = blockIdx.x * NTILE;

  for (int i = tid; i < 192 * 128; i += 512) {
    const int k = i >> 7, n = i & 127;
    sA[n * 192 + (k ^ ((n & 7) << 3))] = f2bf(Wn1[i]);
  }
  for (int i = tid; i < 128 * 64; i += 512) {
    const int k = i >> 6, n = i & 63;
    sB[n * 128 + (k ^ ((n & 7) << 3))] = f2bf(Wn2[i]);
  }
#pragma unroll
  for (int j = 0; j < 8; ++j) {
    const int p = tid + j * 512;
    const int row = p >> 5, col = 2 * (p & 31);
    float2 v = *(const float2*)&nf[(size_t)(node0 + row) * 64 + col];
    *(u32*)&bufN[row * 64 + (col ^ ((row & 7) << 3))] = cvt_pk_bf16(v.x, v.y);
  }
#pragma unroll
  for (int j = 0; j < 16; ++j) {
    const int p = tid + j * 512;
    const int row = p >> 6, col = 2 * (p & 63);
    float2 v = *(const float2*)&agg[(size_t)(node0 + row) * 128 + col];
    *(u32*)&bufA[row * 128 + (col ^ ((row & 7) << 3))] = cvt_pk_bf16(v.x, v.y);
  }
  if (tid < 3 * NTILE) {
    out_c[(size_t)node0 * 3 + tid] =
        coords[(size_t)node0 * 3 + tid] + cdelta[(size_t)node0 * 3 + tid];
  }

  const int lane = tid & 63;
  const int w = tid >> 6;
  const int l15 = lane & 15;
  const int l4 = lane >> 4;
  const int k0l = l4 * 8;

  const int rb1 = (w & 1) * 64;
  const int cb1 = (w >> 1) * 32;
  const int n0 = cb1 + l15, n1 = n0 + 16;
  const float bb1_0 = bn1[n0], bb1_1 = bn1[n1];

  const int rb2 = (w >> 1) * 32;
  const int cb2 = (w & 1) * 32;
  const int n20 = cb2 + l15, n21 = n20 + 16;
  const float bb2_0 = bn2[n20], bb2_1 = bn2[n21];

  __syncthreads();

  f32x4 acc[4][2];
  {
    f32x4 z = {0.f, 0.f, 0.f, 0.f};
#pragma unroll
    for (int i = 0; i < 4; ++i) { acc[i][0] = z; acc[i][1] = z; }
  }
#pragma unroll
  for (int ks = 0; ks < 2; ++ks) {
    const int k = ks * 32 + k0l;
    bf16x8 b0 = *(const bf16x8*)&sA[n0 * 192 + (k ^ ((n0 & 7) << 3))];
    bf16x8 b1 = *(const bf16x8*)&sA[n1 * 192 + (k ^ ((n1 & 7) << 3))];
#pragma unroll
    for (int i = 0; i < 4; ++i) {
      const int row = rb1 + 16 * i + l15;
      bf16x8 a = *(const bf16x8*)&bufN[row * 64 + (k ^ ((row & 7) << 3))];
      acc[i][0] = MFMA(a, b0, acc[i][0]);
      acc[i][1] = MFMA(a, b1, acc[i][1]);
    }
  }
#pragma unroll
  for (int ks = 0; ks < 4; ++ks) {
    const int k = ks * 32 + k0l;
    const int kg = 64 + k;
    bf16x8 b0 = *(const bf16x8*)&sA[n0 * 192 + (kg ^ ((n0 & 7) << 3))];
    bf16x8 b1 = *(const bf16x8*)&sA[n1 * 192 + (kg ^ ((n1 & 7) << 3))];
#pragma unroll
    for (int i = 0; i < 4; ++i) {
      const int row = rb1 + 16 * i + l15;
      bf16x8 a = *(const bf16x8*)&bufA[row * 128 + (k ^ ((row & 7) << 3))];
      acc[i][0] = MFMA(a, b0, acc[i][0]);
      acc[i][1] = MFMA(a, b1, acc[i][1]);
    }
  }
#pragma unroll
  for (int i = 0; i < 4; ++i)
#pragma unroll
    for (int r = 0; r < 4; ++r) {
      const int m = rb1 + 16 * i + l4 * 4 + r;
      hbuf[m * 128 + (n0 ^ ((m & 7) << 3))] = f2bf(silu_f(acc[i][0][r] + bb1_0));
      hbuf[m * 128 + (n1 ^ ((m & 7) << 3))] = f2bf(silu_f(acc[i][1][r] + bb1_1));
    }
  __syncthreads();

  {
    f32x4 z = {0.f, 0.f, 0.f, 0.f};
    acc[0][0] = z; acc[0][1] = z; acc[1][0] = z; acc[1][1] = z;
  }
#pragma unroll
  for (int ks = 0; ks < 4; ++ks) {
    const int k = ks * 32 + k0l;
    bf16x8 b0 = *(const bf16x8*)&sB[n20 * 128 + (k ^ ((n20 & 7) << 3))];
    bf16x8 b1 = *(const bf16x8*)&sB[n21 * 128 + (k ^ ((n21 & 7) << 3))];
    const int r0 = rb2 + l15, r1 = rb2 + 16 + l15;
    bf16x8 a0 = *(const bf16x8*)&hbuf[r0 * 128 + (k ^ ((r0 & 7) << 3))];
    bf16x8 a1 = *(const bf16x8*)&hbuf[r1 * 128 + (k ^ ((r1 & 7) << 3))];
    acc[0][0] = MFMA(a0, b0, acc[0][0]);
    acc[0][1] = MFMA(a0, b1, acc[0][1]);
    acc[1][0] = MFMA(a1, b0, acc[1][0]);
    acc[1][1] = MFMA(a1, b1, acc[1][1]);
  }
#pragma unroll
  for (int i = 0; i < 2; ++i)
#pragma unroll
    for (int r = 0; r < 4; ++r) {
      const int m = rb2 + 16 * i + l4 * 4 + r;
      const size_t base = (size_t)(node0 + m) * 64;
      out_nf[base + n20] = nf[base + n20] + acc[i][0][r] + bb2_0;
      out_nf[base + n21] = nf[base + n21] + acc[i][1][r] + bb2_1;
    }
}

extern "C" void kernel_launch(void* const* d_in, const int* in_sizes, int n_in,
                              void* d_out, int out_size, void* d_ws, size_t ws_size,
                              hipStream_t stream) {
  const float* nf     = (const float*)d_in[0];
  const float* coords = (const float*)d_in[1];
  const int*   ei     = (const int*)d_in[2];
  const float* Wm1 = (const float*)d_in[3];
  const float* bm1 = (const float*)d_in[4];
  const float* Wm2 = (const float*)d_in[5];
  const float* bm2 = (const float*)d_in[6];
  const float* Wn1 = (const float*)d_in[7];
  const float* bn1 = (const float*)d_in[8];
  const float* Wn2 = (const float*)d_in[9];
  const float* bn2 = (const float*)d_in[10];
  const float* Wc1 = (const float*)d_in[11];
  const float* bc1 = (const float*)d_in[12];
  const float* Wc2 = (const float*)d_in[13];
  const float* bc2 = (const float*)d_in[14];

  // ws layout (floats): agg | cdelta | hist(4096 i) | src_s | dst_s | P2(bf16)
  float* agg    = (float*)d_ws;                               // 16 MB
  float* cdelta = agg + (size_t)B_ * N_ * H_;                 // 0.375 MB
  int*   hist   = (int*)(cdelta + (size_t)B_ * N_ * 3);
  int*   src_s  = hist + 4096;
  int*   dst_s  = src_s + E_;
  unsigned short* P2 = (unsigned short*)(dst_s + E_);         // 8.39 MB

  float* out_nf = (float*)d_out;
  float* out_c  = out_nf + (size_t)B_ * N_ * D_;

  // P1 lives in d_out's head; consumed by the edge kernel, then overwritten
  // by the node kernel. Deterministic per call.
  unsigned short* P1 = (unsigned short*)d_out;

  const size_t zero_bytes =
      ((size_t)B_ * N_ * H_ + (size_t)B_ * N_ * 3 + 4096) * sizeof(float);
  hipMemsetAsync(d_ws, 0, zero_bytes, stream);

  p12_k<<<(B_ * N_) / 64, 512, 0, stream>>>(nf, Wm1, bm1, P1, P2);
  hist_k<<<E_ / 256, 256, 0, stream>>>(ei, hist);
  scan4096<<<1, 1024, 0, stream>>>(hist);
  scatter_k<<<E_ / 256, 256, 0, stream>>>(ei, hist, src_s, dst_s);

  egnn_edge_mfma<<<EDGE_BLOCKS, 512, 0, stream>>>(
      P1, P2, coords, src_s, dst_s, Wm1, Wm2, bm2, Wc1, bc1, Wc2, bc2,
      agg, cdelta);
  egnn_node_mfma<<<(B_ * N_) / NTILE, 512, 0, stream>>>(
      nf, coords, agg, cdelta, Wn1, bn1, Wn2, bn2, out_nf, out_c);
}

// Round 16
// 371.464 us; speedup vs baseline: 1.0736x; 1.0736x over previous
//
#include <hip/hip_runtime.h>
#include <hip/hip_bf16.h>

#define B_ 8
#define N_ 4096
#define E_ 131072
#define D_ 64
#define H_ 128

#define EDGE_BLOCKS 256
#define ETILE 128
#define TILES_TOTAL ((B_ * E_) / ETILE)               // 8192 tiles of 128 edges
#define TILES_PER_BLOCK (TILES_TOTAL / EDGE_BLOCKS)   // 32

typedef unsigned int u32;
typedef short bf16x8 __attribute__((ext_vector_type(8)));
typedef float f32x4 __attribute__((ext_vector_type(4)));

__device__ __forceinline__ unsigned short f2bf(float f) {
  u32 x = __float_as_uint(f);
  x += 0x7fffu + ((x >> 16) & 1u);   // RNE
  return (unsigned short)(x >> 16);
}
__device__ __forceinline__ float bf2f(unsigned short v) {
  return __uint_as_float(((u32)v) << 16);
}
__device__ __forceinline__ u32 cvt_pk_bf16(float lo, float hi) {
  u32 r;
  asm("v_cvt_pk_bf16_f32 %0, %1, %2" : "=v"(r) : "v"(lo), "v"(hi));
  return r;
}
__device__ __forceinline__ float silu_f(float x) { return x / (1.0f + __expf(-x)); }

// XOR-swizzled u16 index into a [rows][128] bf16 LDS tile (row stride 256 B).
__device__ __forceinline__ int swz(int row, int col) {
  return row * 128 + (col ^ ((row & 7) << 3));
}

#define MFMA(a, b, c) __builtin_amdgcn_mfma_f32_16x16x32_bf16(a, b, c, 0, 0, 0)

// ---------------- prep kernels ----------------
// P1[n] = nf[n] @ Wm1[0:64,:] + bm1 ; P2[n] = nf[n] @ Wm1[64:128,:]  (bf16 out)
__global__ __launch_bounds__(512) void p12_k(
    const float* __restrict__ nf, const float* __restrict__ Wm1,
    const float* __restrict__ bm1,
    unsigned short* __restrict__ P1, unsigned short* __restrict__ P2)
{
  __shared__ unsigned short sWa[128 * 64];   // [outcol][k], Wm1 rows 0-63
  __shared__ unsigned short sWb[128 * 64];   // Wm1 rows 64-127
  __shared__ unsigned short sNf[64 * 64];    // nf tile bf16

  const int tid = threadIdx.x;
  const int node0 = blockIdx.x * 64;

  for (int i = tid; i < 64 * 128; i += 512) {
    const int k = i >> 7, n = i & 127;
    const int d = n * 64 + (k ^ ((n & 7) << 3));
    sWa[d] = f2bf(Wm1[k * 128 + n]);
    sWb[d] = f2bf(Wm1[(64 + k) * 128 + n]);
  }
  {
    const int row = tid >> 3, c0 = 8 * (tid & 7);
    const float4 v0 = *(const float4*)&nf[(size_t)(node0 + row) * 64 + c0];
    const float4 v1 = *(const float4*)&nf[(size_t)(node0 + row) * 64 + c0 + 4];
    uint4 pk = make_uint4(cvt_pk_bf16(v0.x, v0.y), cvt_pk_bf16(v0.z, v0.w),
                          cvt_pk_bf16(v1.x, v1.y), cvt_pk_bf16(v1.z, v1.w));
    *(uint4*)&sNf[row * 64 + (c0 ^ ((row & 7) << 3))] = pk;
  }
  __syncthreads();

  const int lane = tid & 63;
  const int w = tid >> 6;              // 8 waves: w<4 -> P1 cols, w>=4 -> P2
  const int l15 = lane & 15;
  const int l4 = lane >> 4;
  const int k0l = l4 * 8;
  const int colbase = (w & 3) * 32;
  const int n0 = colbase + l15, n1 = n0 + 16;
  const unsigned short* sW = (w < 4) ? sWa : sWb;
  const float add0 = (w < 4) ? bm1[n0] : 0.f;
  const float add1 = (w < 4) ? bm1[n1] : 0.f;
  unsigned short* OUT = (w < 4) ? P1 : P2;

  f32x4 acc[4][2];
  {
    f32x4 z = {0.f, 0.f, 0.f, 0.f};
#pragma unroll
    for (int i = 0; i < 4; ++i) { acc[i][0] = z; acc[i][1] = z; }
  }
#pragma unroll
  for (int ks = 0; ks < 2; ++ks) {
    const int k = ks * 32 + k0l;
    bf16x8 b0 = *(const bf16x8*)&sW[n0 * 64 + (k ^ ((n0 & 7) << 3))];
    bf16x8 b1 = *(const bf16x8*)&sW[n1 * 64 + (k ^ ((n1 & 7) << 3))];
#pragma unroll
    for (int i = 0; i < 4; ++i) {
      const int row = 16 * i + l15;
      bf16x8 a = *(const bf16x8*)&sNf[row * 64 + (k ^ ((row & 7) << 3))];
      acc[i][0] = MFMA(a, b0, acc[i][0]);
      acc[i][1] = MFMA(a, b1, acc[i][1]);
    }
  }
#pragma unroll
  for (int i = 0; i < 4; ++i)
#pragma unroll
    for (int r = 0; r < 4; ++r) {
      const int m = 16 * i + l4 * 4 + r;
      OUT[(size_t)(node0 + m) * 128 + n0] = f2bf(acc[i][0][r] + add0);
      OUT[(size_t)(node0 + m) * 128 + n1] = f2bf(acc[i][1][r] + add1);
    }
}

__global__ void hist_k(const int* __restrict__ ei, int* __restrict__ hist) {
  const int e = blockIdx.x * 256 + threadIdx.x;
  atomicAdd(&hist[ei[E_ + e]], 1);
}

__global__ __launch_bounds__(1024) void scan4096(int* __restrict__ h) {
  __shared__ int wsums[16];
  const int tid = threadIdx.x;
  const int lane = tid & 63, wv = tid >> 6;
  int4 v = ((int4*)h)[tid];
  const int s = v.x + v.y + v.z + v.w;
  int incl = s;
#pragma unroll
  for (int off = 1; off < 64; off <<= 1) {
    int u = __shfl_up(incl, off);
    if (lane >= off) incl += u;
  }
  if (lane == 63) wsums[wv] = incl;
  __syncthreads();
  if (wv == 0) {
    int ws = (lane < 16) ? wsums[lane] : 0;
#pragma unroll
    for (int off = 1; off < 16; off <<= 1) {
      int u = __shfl_up(ws, off);
      if (lane >= off) ws += u;
    }
    if (lane < 16) wsums[lane] = ws;
  }
  __syncthreads();
  int base = (wv ? wsums[wv - 1] : 0) + (incl - s);
  int4 o;
  o.x = base; o.y = base + v.x; o.z = o.y + v.y; o.w = o.z + v.z;
  ((int4*)h)[tid] = o;
}

__global__ void scatter_k(const int* __restrict__ ei, int* __restrict__ offs,
                          int* __restrict__ src_s, int* __restrict__ dst_s) {
  const int e = blockIdx.x * 256 + threadIdx.x;
  const int d = ei[E_ + e];
  const int p = atomicAdd(&offs[d], 1);
  src_s[p] = ei[e];
  dst_s[p] = d;
}

// ------ edge kernel: L1 folded into gather via P1/P2; ping-pong; 3 barriers ------
__global__ __launch_bounds__(1024, 4) void egnn_edge_mfma(
    const unsigned short* __restrict__ P1, const unsigned short* __restrict__ P2,
    const float* __restrict__ coords,
    const int* __restrict__ src_s, const int* __restrict__ dst_s,
    const float* __restrict__ Wm1,
    const float* __restrict__ Wm2, const float* __restrict__ bm2,
    const float* __restrict__ Wc1, const float* __restrict__ bc1,
    const float* __restrict__ Wc2, const float* __restrict__ bc2,
    float* __restrict__ agg, float* __restrict__ cdelta)
{
  __shared__ unsigned short sW2[128 * 128];       // 32 KB (Wm2^T swizzled)
  __shared__ unsigned short sW3[128 * 128];       // 32 KB (Wc1^T)
  __shared__ unsigned short bufA[ETILE * 128];    // 32 KB: h tile
  __shared__ unsigned short bufB[ETILE * 128];    // 32 KB: m tile
  __shared__ float swr[128];                      // Wm1 row 128 (dist weights)
  __shared__ float4 sgeo[2][ETILE];
  __shared__ int sdst[2][ETILE];
  __shared__ float swpart[4][ETILE];

  const int tid = threadIdx.x;
  for (int i = tid; i < 128 * 128; i += 1024) {
    const int k = i >> 7, n = i & 127;
    const int d = swz(n, k);
    sW2[d] = f2bf(Wm2[i]);
    sW3[d] = f2bf(Wc1[i]);
  }
  if (tid < 128) swr[tid] = Wm1[128 * 128 + tid];

  const int lane = tid & 63;
  const int w = tid >> 6;
  const int l15 = lane & 15;
  const int l4 = lane >> 4;
  const int k0l = l4 * 8;
  const int rowbase = (w >> 2) * 32;   // {0,32,64,96}
  const int colbase = (w & 3) * 32;
  const int rA = rowbase + l15;
  const int rB = colbase + l15;
  const int n0 = colbase + l15;
  const int n1 = n0 + 16;

  const float bb2_0 = bm2[n0], bb2_1 = bm2[n1];
  const float bb3_0 = bc1[n0], bb3_1 = bc1[n1];
  const float wc2_0 = Wc2[n0], wc2_1 = Wc2[n1];
  const float bc2v = bc2[0];

  const int m_t = tid >> 3;   // gather: 8 threads per edge row
  const int q_t = tid & 7;    // 16-col group per thread

  // XCD swizzle: batch b owned by one XCD
  const int myblk = (blockIdx.x & 7) * (EDGE_BLOCKS / 8) + (blockIdx.x >> 3);
  const int b = myblk >> 5;                     // 32 blocks per batch
  const int gbase = (myblk & 31) * TILES_PER_BLOCK;

  __syncthreads();

  f32x4 acc[2][2];

  for (int t = 0; t < TILES_PER_BLOCK; ++t) {
    const int p = t & 1;
    const int ebase = (gbase + t) * ETILE;

    // ---- gather + fused L1: h = silu(P1[s] + P2[d] + dist*wr) -> bufA ----
    {
      const int e = ebase + m_t;
      const int s = src_s[e];
      const int d = dst_s[e];
      const float* cs = coords + (size_t)(b * N_ + s) * 3;
      const float* cd = coords + (size_t)(b * N_ + d) * 3;
      const float d0 = cd[0] - cs[0], d1 = cd[1] - cs[1], d2 = cd[2] - cs[2];
      const float dist = sqrtf(fmaf(d0, d0, fmaf(d1, d1, d2 * d2)));
      if (q_t == 0) {
        sdst[p][m_t] = d;
        sgeo[p][m_t] = make_float4(d0, d1, d2, dist);
      }
      const int c0 = 16 * q_t;
      const uint4* p1p = (const uint4*)(P1 + (size_t)(b * N_ + s) * 128 + c0);
      const uint4* p2p = (const uint4*)(P2 + (size_t)(b * N_ + d) * 128 + c0);
      uint4 xa = p1p[0], xb = p1p[1];
      uint4 ya = p2p[0], yb = p2p[1];
      u32 opk[8];
#pragma unroll
      for (int jj = 0; jj < 4; ++jj) {
        const float2 wr2 = *(const float2*)&swr[c0 + 2 * jj];
        const u32 xp = ((const u32*)&xa)[jj], yp = ((const u32*)&ya)[jj];
        const float lo = bf2f((unsigned short)xp) + bf2f((unsigned short)yp) + dist * wr2.x;
        const float hi = bf2f((unsigned short)(xp >> 16)) + bf2f((unsigned short)(yp >> 16)) + dist * wr2.y;
        opk[jj] = cvt_pk_bf16(silu_f(lo), silu_f(hi));
      }
#pragma unroll
      for (int jj = 0; jj < 4; ++jj) {
        const float2 wr2 = *(const float2*)&swr[c0 + 8 + 2 * jj];
        const u32 xp = ((const u32*)&xb)[jj], yp = ((const u32*)&yb)[jj];
        const float lo = bf2f((unsigned short)xp) + bf2f((unsigned short)yp) + dist * wr2.x;
        const float hi = bf2f((unsigned short)(xp >> 16)) + bf2f((unsigned short)(yp >> 16)) + dist * wr2.y;
        opk[4 + jj] = cvt_pk_bf16(silu_f(lo), silu_f(hi));
      }
      *(uint4*)&bufA[swz(m_t, c0)] = make_uint4(opk[0], opk[1], opk[2], opk[3]);
      *(uint4*)&bufA[swz(m_t, c0 + 8)] = make_uint4(opk[4], opk[5], opk[6], opk[7]);
    }
    __syncthreads();   // B1: h visible in bufA

    // ---- L2: m = h @ Wm2 + bm2 -> bufB (no intermediate barrier) ----
    {
      f32x4 z = {0.f, 0.f, 0.f, 0.f};
      acc[0][0] = z; acc[0][1] = z; acc[1][0] = z; acc[1][1] = z;
    }
#pragma unroll
    for (int ks = 0; ks < 4; ++ks) {
      const int k = ks * 32 + k0l;
      bf16x8 b0 = *(const bf16x8*)&sW2[swz(rB, k)];
      bf16x8 b1 = *(const bf16x8*)&sW2[swz(rB + 16, k)];
      bf16x8 a0 = *(const bf16x8*)&bufA[swz(rA, k)];
      bf16x8 a1 = *(const bf16x8*)&bufA[swz(rA + 16, k)];
      acc[0][0] = MFMA(a0, b0, acc[0][0]);
      acc[0][1] = MFMA(a0, b1, acc[0][1]);
      acc[1][0] = MFMA(a1, b0, acc[1][0]);
      acc[1][1] = MFMA(a1, b1, acc[1][1]);
    }
#pragma unroll
    for (int i = 0; i < 2; ++i)
#pragma unroll
      for (int r = 0; r < 4; ++r) {
        const int m = rowbase + 16 * i + l4 * 4 + r;
        const u32 pk = cvt_pk_bf16(acc[i][0][r] + bb2_0, acc[i][1][r] + bb2_1);
        bufB[swz(m, n0)] = (unsigned short)pk;
        bufB[swz(m, n1)] = (unsigned short)(pk >> 16);
      }
    __syncthreads();   // B2: m visible in bufB

    // ---- L3: c = silu(m @ Wc1 + bc1); partial w = c . Wc2 ----
    {
      f32x4 z = {0.f, 0.f, 0.f, 0.f};
      acc[0][0] = z; acc[0][1] = z; acc[1][0] = z; acc[1][1] = z;
    }
#pragma unroll
    for (int ks = 0; ks < 4; ++ks) {
      const int k = ks * 32 + k0l;
      bf16x8 b0 = *(const bf16x8*)&sW3[swz(rB, k)];
      bf16x8 b1 = *(const bf16x8*)&sW3[swz(rB + 16, k)];
      bf16x8 a0 = *(const bf16x8*)&bufB[swz(rA, k)];
      bf16x8 a1 = *(const bf16x8*)&bufB[swz(rA + 16, k)];
      acc[0][0] = MFMA(a0, b0, acc[0][0]);
      acc[0][1] = MFMA(a0, b1, acc[0][1]);
      acc[1][0] = MFMA(a1, b0, acc[1][0]);
      acc[1][1] = MFMA(a1, b1, acc[1][1]);
    }
#pragma unroll
    for (int i = 0; i < 2; ++i)
#pragma unroll
      for (int r = 0; r < 4; ++r) {
        float pw = silu_f(acc[i][0][r] + bb3_0) * wc2_0 +
                   silu_f(acc[i][1][r] + bb3_1) * wc2_1;
        pw += __shfl_xor(pw, 1);
        pw += __shfl_xor(pw, 2);
        pw += __shfl_xor(pw, 4);
        pw += __shfl_xor(pw, 8);
        if (l15 == 0) swpart[w & 3][rowbase + 16 * i + l4 * 4 + r] = pw;
      }

    // ---- agg run-reduction: 1024 thr, (colpair=tid&63, 8-row group=tid>>6) ----
    {
      const int c0 = 2 * (tid & 63);
      int r = (tid >> 6) * 8;           // wave-uniform row group
      int cur = sdst[p][r];
      float a0s = 0.f, a1s = 0.f;
#pragma unroll 4
      for (int k = 0; k < 8; ++k, ++r) {
        const int d2 = sdst[p][r];
        if (d2 != cur) {   // uniform per wave
          float* bp2 = agg + ((size_t)(b * N_ + cur)) * H_ + c0;
          unsafeAtomicAdd(bp2, a0s);
          unsafeAtomicAdd(bp2 + 1, a1s);
          a0s = 0.f; a1s = 0.f;
          cur = d2;
        }
        const u32 pkr = *(const u32*)&bufB[swz(r, c0)];
        a0s += bf2f((unsigned short)pkr);
        a1s += bf2f((unsigned short)(pkr >> 16));
      }
      float* bp2 = agg + ((size_t)(b * N_ + cur)) * H_ + c0;
      unsafeAtomicAdd(bp2, a0s);
      unsafeAtomicAdd(bp2 + 1, a1s);
    }
    __syncthreads();   // B3: bufB reads done, swpart visible

    // ---- coord scatter: segmented scan over 128 sorted rows (waves 0,1) ----
    if (tid < ETILE) {
      float wc = bc2v;
#pragma unroll
      for (int cg = 0; cg < 4; ++cg) wc += swpart[cg][tid];
      const float4 g = sgeo[p][tid];
      const float inv = 1.0f / (g.w + 1e-8f);
      float vx = wc * g.x * inv, vy = wc * g.y * inv, vz = wc * g.z * inv;
      const int myd = sdst[p][tid];
      int flg = (lane == 0) ? 1 : (sdst[p][tid - 1] != myd);
#pragma unroll
      for (int off = 1; off < 64; off <<= 1) {
        float ux = __shfl_up(vx, off);
        float uy = __shfl_up(vy, off);
        float uz = __shfl_up(vz, off);
        int uf = __shfl_up(flg, off);
        if (lane >= off) {
          if (!flg) { vx += ux; vy += uy; vz += uz; }
          flg |= uf;
        }
      }
      const bool tail = (lane == 63) || (sdst[p][tid + 1] != myd);
      if (tail) {
        float* bp = cdelta + ((size_t)(b * N_ + myd)) * 3;
        unsafeAtomicAdd(bp + 0, vx);
        unsafeAtomicAdd(bp + 1, vy);
        unsafeAtomicAdd(bp + 2, vz);
      }
    }
    // next gather writes bufA (last read pre-B2) + parity p^1 geo: safe
  }
}

// ---------------- node kernel: MFMA version ----------------
#define NTILE 128

__global__ __launch_bounds__(512) void egnn_node_mfma(
    const float* __restrict__ nf, const float* __restrict__ coords,
    const float* __restrict__ agg, const float* __restrict__ cdelta,
    const float* __restrict__ Wn1, const float* __restrict__ bn1,
    const float* __restrict__ Wn2, const float* __restrict__ bn2,
    float* __restrict__ out_nf, float* __restrict__ out_c)
{
  __shared__ unsigned short sA[128 * 192];
  __shared__ unsigned short sB[64 * 128];
  __shared__ unsigned short bufN[128 * 64];
  __shared__ unsigned short bufA[128 * 128];
  __shared__ unsigned short hbuf[128 * 128];

  const int tid = threadIdx.x;
  const int node0 = blockIdx.x * NTILE;

  for (int i = tid; i < 192 * 128; i += 512) {
    const int k = i >> 7, n = i & 127;
    sA[n * 192 + (k ^ ((n & 7) << 3))] = f2bf(Wn1[i]);
  }
  for (int i = tid; i < 128 * 64; i += 512) {
    const int k = i >> 6, n = i & 63;
    sB[n * 128 + (k ^ ((n & 7) << 3))] = f2bf(Wn2[i]);
  }
#pragma unroll
  for (int j = 0; j < 8; ++j) {
    const int p = tid + j * 512;
    const int row = p >> 5, col = 2 * (p & 31);
    float2 v = *(const float2*)&nf[(size_t)(node0 + row) * 64 + col];
    *(u32*)&bufN[row * 64 + (col ^ ((row & 7) << 3))] = cvt_pk_bf16(v.x, v.y);
  }
#pragma unroll
  for (int j = 0; j < 16; ++j) {
    const int p = tid + j * 512;
    const int row = p >> 6, col = 2 * (p & 63);
    float2 v = *(const float2*)&agg[(size_t)(node0 + row) * 128 + col];
    *(u32*)&bufA[row * 128 + (col ^ ((row & 7) << 3))] = cvt_pk_bf16(v.x, v.y);
  }
  if (tid < 3 * NTILE) {
    out_c[(size_t)node0 * 3 + tid] =
        coords[(size_t)node0 * 3 + tid] + cdelta[(size_t)node0 * 3 + tid];
  }

  const int lane = tid & 63;
  const int w = tid >> 6;
  const int l15 = lane & 15;
  const int l4 = lane >> 4;
  const int k0l = l4 * 8;

  const int rb1 = (w & 1) * 64;
  const int cb1 = (w >> 1) * 32;
  const int n0 = cb1 + l15, n1 = n0 + 16;
  const float bb1_0 = bn1[n0], bb1_1 = bn1[n1];

  const int rb2 = (w >> 1) * 32;
  const int cb2 = (w & 1) * 32;
  const int n20 = cb2 + l15, n21 = n20 + 16;
  const float bb2_0 = bn2[n20], bb2_1 = bn2[n21];

  __syncthreads();

  f32x4 acc[4][2];
  {
    f32x4 z = {0.f, 0.f, 0.f, 0.f};
#pragma unroll
    for (int i = 0; i < 4; ++i) { acc[i][0] = z; acc[i][1] = z; }
  }
#pragma unroll
  for (int ks = 0; ks < 2; ++ks) {
    const int k = ks * 32 + k0l;
    bf16x8 b0 = *(const bf16x8*)&sA[n0 * 192 + (k ^ ((n0 & 7) << 3))];
    bf16x8 b1 = *(const bf16x8*)&sA[n1 * 192 + (k ^ ((n1 & 7) << 3))];
#pragma unroll
    for (int i = 0; i < 4; ++i) {
      const int row = rb1 + 16 * i + l15;
      bf16x8 a = *(const bf16x8*)&bufN[row * 64 + (k ^ ((row & 7) << 3))];
      acc[i][0] = MFMA(a, b0, acc[i][0]);
      acc[i][1] = MFMA(a, b1, acc[i][1]);
    }
  }
#pragma unroll
  for (int ks = 0; ks < 4; ++ks) {
    const int k = ks * 32 + k0l;
    const int kg = 64 + k;
    bf16x8 b0 = *(const bf16x8*)&sA[n0 * 192 + (kg ^ ((n0 & 7) << 3))];
    bf16x8 b1 = *(const bf16x8*)&sA[n1 * 192 + (kg ^ ((n1 & 7) << 3))];
#pragma unroll
    for (int i = 0; i < 4; ++i) {
      const int row = rb1 + 16 * i + l15;
      bf16x8 a = *(const bf16x8*)&bufA[row * 128 + (k ^ ((row & 7) << 3))];
      acc[i][0] = MFMA(a, b0, acc[i][0]);
      acc[i][1] = MFMA(a, b1, acc[i][1]);
    }
  }
#pragma unroll
  for (int i = 0; i < 4; ++i)
#pragma unroll
    for (int r = 0; r < 4; ++r) {
      const int m = rb1 + 16 * i + l4 * 4 + r;
      hbuf[m * 128 + (n0 ^ ((m & 7) << 3))] = f2bf(silu_f(acc[i][0][r] + bb1_0));
      hbuf[m * 128 + (n1 ^ ((m & 7) << 3))] = f2bf(silu_f(acc[i][1][r] + bb1_1));
    }
  __syncthreads();

  {
    f32x4 z = {0.f, 0.f, 0.f, 0.f};
    acc[0][0] = z; acc[0][1] = z; acc[1][0] = z; acc[1][1] = z;
  }
#pragma unroll
  for (int ks = 0; ks < 4; ++ks) {
    const int k = ks * 32 + k0l;
    bf16x8 b0 = *(const bf16x8*)&sB[n20 * 128 + (k ^ ((n20 & 7) << 3))];
    bf16x8 b1 = *(const bf16x8*)&sB[n21 * 128 + (k ^ ((n21 & 7) << 3))];
    const int r0 = rb2 + l15, r1 = rb2 + 16 + l15;
    bf16x8 a0 = *(const bf16x8*)&hbuf[r0 * 128 + (k ^ ((r0 & 7) << 3))];
    bf16x8 a1 = *(const bf16x8*)&hbuf[r1 * 128 + (k ^ ((r1 & 7) << 3))];
    acc[0][0] = MFMA(a0, b0, acc[0][0]);
    acc[0][1] = MFMA(a0, b1, acc[0][1]);
    acc[1][0] = MFMA(a1, b0, acc[1][0]);
    acc[1][1] = MFMA(a1, b1, acc[1][1]);
  }
#pragma unroll
  for (int i = 0; i < 2; ++i)
#pragma unroll
    for (int r = 0; r < 4; ++r) {
      const int m = rb2 + 16 * i + l4 * 4 + r;
      const size_t base = (size_t)(node0 + m) * 64;
      out_nf[base + n20] = nf[base + n20] + acc[i][0][r] + bb2_0;
      out_nf[base + n21] = nf[base + n21] + acc[i][1][r] + bb2_1;
    }
}

extern "C" void kernel_launch(void* const* d_in, const int* in_sizes, int n_in,
                              void* d_out, int out_size, void* d_ws, size_t ws_size,
                              hipStream_t stream) {
  const float* nf     = (const float*)d_in[0];
  const float* coords = (const float*)d_in[1];
  const int*   ei     = (const int*)d_in[2];
  const float* Wm1 = (const float*)d_in[3];
  const float* bm1 = (const float*)d_in[4];
  const float* Wm2 = (const float*)d_in[5];
  const float* bm2 = (const float*)d_in[6];
  const float* Wn1 = (const float*)d_in[7];
  const float* bn1 = (const float*)d_in[8];
  const float* Wn2 = (const float*)d_in[9];
  const float* bn2 = (const float*)d_in[10];
  const float* Wc1 = (const float*)d_in[11];
  const float* bc1 = (const float*)d_in[12];
  const float* Wc2 = (const float*)d_in[13];
  const float* bc2 = (const float*)d_in[14];

  // ws layout (floats): agg | cdelta | hist(4096 i) | src_s | dst_s | P2(bf16)
  float* agg    = (float*)d_ws;                               // 16 MB
  float* cdelta = agg + (size_t)B_ * N_ * H_;                 // 0.375 MB
  int*   hist   = (int*)(cdelta + (size_t)B_ * N_ * 3);
  int*   src_s  = hist + 4096;
  int*   dst_s  = src_s + E_;
  unsigned short* P2 = (unsigned short*)(dst_s + E_);         // 8.39 MB

  float* out_nf = (float*)d_out;
  float* out_c  = out_nf + (size_t)B_ * N_ * D_;

  // P1 lives in d_out's head (exactly out_nf's 8.39 MB slot); consumed by the
  // edge kernel, then overwritten by the node kernel. Deterministic per call.
  unsigned short* P1 = (unsigned short*)d_out;

  const size_t zero_bytes =
      ((size_t)B_ * N_ * H_ + (size_t)B_ * N_ * 3 + 4096) * sizeof(float);
  hipMemsetAsync(d_ws, 0, zero_bytes, stream);

  p12_k<<<(B_ * N_) / 64, 512, 0, stream>>>(nf, Wm1, bm1, P1, P2);
  hist_k<<<E_ / 256, 256, 0, stream>>>(ei, hist);
  scan4096<<<1, 1024, 0, stream>>>(hist);
  scatter_k<<<E_ / 256, 256, 0, stream>>>(ei, hist, src_s, dst_s);

  egnn_edge_mfma<<<EDGE_BLOCKS, 1024, 0, stream>>>(
      P1, P2, coords, src_s, dst_s, Wm1, Wm2, bm2, Wc1, bc1, Wc2, bc2,
      agg, cdelta);
  egnn_node_mfma<<<(B_ * N_) / NTILE, 512, 0, stream>>>(
      nf, coords, agg, cdelta, Wn1, bn1, Wn2, bn2, out_nf, out_c);
}